// Round 3
// baseline (185.407 us; speedup 1.0000x reference)
//
#include <hip/hip_runtime.h>
#include <math.h>

// Problem constants (fixed by setup_inputs)
#define BATCH 32768
#define SS 16          // bands / sequence
#define DI 14          // input dim
#define BQ 256         // stored patterns
#define NC 7           // classes
#define NBLK 4096      // 4 waves/block x 2 batches/wave -> 32768 batches exactly

// ws layout:
//   mpack : double2[7][256]  (28672 B) m-tilde = g_sp*k - (S/14), packed dim-pairs x pattern
//   Tf    : float[256*7]     ( 7168 B) per-pattern class contribution table
//   zb    : double[7]        (   56 B) bm[c]*sum(Wb) + bb
//   cvec  : double[256]      ( 2048 B) c_j = b_sp . k_j   (all 0 for these inputs)
//   hc    : int              (    4 B) any(b_sp != 0)
#define WS_MPACK_OFF 0
#define WS_TF_OFF    28672
#define WS_ZB_OFF    35840
#define WS_CV_OFF    35896
#define WS_HC_OFF    37944

typedef float  f32x4 __attribute__((ext_vector_type(4)));
typedef short  s16x8 __attribute__((ext_vector_type(8)));
typedef float  v2f   __attribute__((ext_vector_type(2)));

__device__ __forceinline__ unsigned short bf16_rne(float f) {
    unsigned u = __float_as_uint(f);
    unsigned r = u + 0x7FFFu + ((u >> 16) & 1u);
    return (unsigned short)(r >> 16);
}
__device__ __forceinline__ float bf16_to_f32(unsigned short h) {
    return __uint_as_float(((unsigned)h) << 16);
}

// Monotone fp32->u32 order map, top 24 bits kept, low byte = (255-j).
// u32 compare == "score desc, then lowest j" at 2^-16 relative quantization —
// below the bf16-split scan error; fp64 rescore covers both error tiers.
__device__ __forceinline__ unsigned key32(float v, int j) {
    unsigned u = __float_as_uint(v);
    u ^= ((unsigned)((int)u >> 31)) | 0x80000000u;
    return (u & 0xFFFFFF00u) | (unsigned)(255 - j);
}

// xor-butterfly exchange via ds_swizzle (immediate pattern, no address VALU).
// BitMode offset = (xor<<10) | (or<<5) | and, and=0x1F, or=0.
template<int PAT>
__device__ __forceinline__ unsigned swz(unsigned v) {
    return (unsigned)__builtin_amdgcn_ds_swizzle((int)v, PAT);
}

__global__ __launch_bounds__(256) void precompute_kernel(
    const float* __restrict__ lookup,
    const float* __restrict__ g_st, const float* __restrict__ b_st,
    const float* __restrict__ g_pp, const float* __restrict__ b_pp,
    const float* __restrict__ g_sp, const float* __restrict__ b_sp,
    const float* __restrict__ Wv,  const float* __restrict__ Wo,
    const float* __restrict__ Wm,  const float* __restrict__ bm,
    const float* __restrict__ Wb,  const float* __restrict__ bb,
    double2* __restrict__ mpack, float* __restrict__ Tf, double* __restrict__ zb,
    double* __restrict__ cvec, int* __restrict__ hc)
{
    __shared__ double G1s[256][7];   // (Wo.T @ Wm.T)  : [p][c]
    __shared__ double Gs[14][7];     // Wv.T @ G1      : [d][c]
    const int tid = threadIdx.x;

    // G1[p][c] = sum_o Wo[o,p] * Wm[c,o]
    {
        const int p = tid;
        for (int c = 0; c < NC; ++c) {
            double acc = 0.0;
            for (int o = 0; o < 28; ++o)
                acc += (double)Wo[o * 256 + p] * (double)Wm[c * 28 + o];
            G1s[p][c] = acc;
        }
    }
    __syncthreads();
    // G[d][c] = sum_p Wv[p,d] * G1[p][c]
    if (tid < DI * NC) {
        const int d = tid / NC, c = tid % NC;
        double acc = 0.0;
        for (int p = 0; p < 256; ++p)
            acc += (double)Wv[p * DI + d] * G1s[p][c];
        Gs[d][c] = acc;
    }
    __syncthreads();

    // Per stored pattern j: LayerNorm once (fp64), emit m-tilde, c_j, T row.
    {
        const int j = tid;
        double xr[DI];
        double sum = 0.0;
        for (int d = 0; d < DI; ++d) { xr[d] = (double)lookup[j * DI + d]; sum += xr[d]; }
        const double mu = sum * (1.0 / (double)DI);
        double vs = 0.0;
        for (int d = 0; d < DI; ++d) { const double t = xr[d] - mu; vs += t * t; }
        const double rs = 1.0 / sqrt(vs * (1.0 / (double)DI) + 1e-5);

        double kj[DI], vl[DI];
        for (int d = 0; d < DI; ++d) {
            const double nrm = (xr[d] - mu) * rs;
            kj[d] = nrm * (double)g_st[d] + (double)b_st[d];
            vl[d] = nrm * (double)g_pp[d] + (double)b_pp[d];
        }
        // m_j = g_sp .* k_j ; m~_j = m_j - (sum m_j)/14 ; c_j = b_sp . k_j
        double mv[DI], S = 0.0, cj = 0.0;
        for (int d = 0; d < DI; ++d) {
            mv[d] = kj[d] * (double)g_sp[d];
            S += mv[d];
            cj += (double)b_sp[d] * kj[d];
        }
        const double Sm = S * (1.0 / (double)DI);
        for (int d2 = 0; d2 < DI / 2; ++d2) {
            double2 p; p.x = mv[2 * d2] - Sm; p.y = mv[2 * d2 + 1] - Sm;
            mpack[d2 * 256 + j] = p;
        }
        cvec[j] = cj;

        for (int c = 0; c < NC; ++c) {
            double acc = 0.0;
            for (int d = 0; d < DI; ++d) acc += vl[d] * Gs[d][c];
            Tf[j * NC + c] = (float)acc;
        }
    }
    if (tid < NC) {
        double wbsum = 0.0;
        for (int s = 0; s < SS; ++s) wbsum += (double)Wb[s];
        zb[tid] = (double)bm[tid] * wbsum + (double)bb[0];
    }
    if (tid == 0) {
        int f = 0;
        for (int d = 0; d < DI; ++d) f |= (b_sp[d] != 0.0f) ? 1 : 0;
        *hc = f;
    }
}

// One wave = 2 contiguous batches (single superstep).
// Tile loop outermost (B frags read once per tile per wave), batches inner.
// 3-term bf16-split MFMA scan; parity trackers; u32-key top-2 tournament via
// ds_swizzle; fp64 rescore (1 task/lane) makes the final pick.
__global__ __launch_bounds__(256, 4) void hopfield_kernel(
    const float* __restrict__ x,
    const double2* __restrict__ mpack, const double* __restrict__ cvec,
    const int* __restrict__ hcp,
    const float* __restrict__ Tf, const double* __restrict__ zb,
    const float* __restrict__ Wb, float* __restrict__ out)
{
    __shared__ s16x8  bhiS[512];              // B hi frags [tile][slab*16+col]  8 KiB
    __shared__ s16x8  bloS[512];              // B lo frags                      8 KiB
    __shared__ float  Ts[256 * NC];           //                                 7 KiB
    __shared__ double zbs[NC];
    __shared__ float  wbs[SS];
    __shared__ int    jcandS[4][2][SS][2];    // [wave][bi][row][cand]
    __shared__ int    jstarS[4][2][SS];
    __shared__ double zrowd[4][2][NC];
    __shared__ float  irsS[4][2][SS];         // general path only (hc != 0)

    const int tid  = threadIdx.x;
    const int lane = tid & 63;
    const int w    = tid >> 6;
    const int g    = lane >> 4;   // A k-slab / C row-group
    const int l    = lane & 15;   // A row (band) / C col (pattern sub-idx)
    const int hc   = *hcp;

    // ---- stage B fragments (hi/lo bf16 splits), thread tid = pattern j ----
    {
        const int j = tid;
        float mf[16];
        #pragma unroll
        for (int d2 = 0; d2 < 7; ++d2) {
            const double2 mv = mpack[d2 * 256 + j];
            mf[2 * d2] = (float)mv.x; mf[2 * d2 + 1] = (float)mv.y;
        }
        mf[14] = (float)cvec[j];   // pairs with A dim14 = irs (general path; 0 here)
        mf[15] = 0.f;
        #pragma unroll
        for (int ks = 0; ks < 2; ++ks) {
            s16x8 h8, l8;
            #pragma unroll
            for (int i = 0; i < 8; ++i) {
                const float f = mf[8 * ks + i];
                const unsigned short h = bf16_rne(f);
                const float r = f - bf16_to_f32(h);     // exact (Sterbenz)
                h8[i] = (short)h;
                l8[i] = (short)bf16_rne(r);
            }
            bhiS[(j >> 4) * 32 + ks * 16 + (j & 15)] = h8;
            bloS[(j >> 4) * 32 + ks * 16 + (j & 15)] = l8;
        }
    }
    for (int i = tid; i < 256 * NC; i += 256) Ts[i] = Tf[i];
    if (tid < NC) zbs[tid] = zb[tid];
    if (tid < SS) wbs[tid] = Wb[tid];
    __syncthreads();

    const int gw = blockIdx.x * 4 + w;               // 0..16383
    const float* xw = x + (size_t)gw * 2 * SS * DI;  // this wave's 2 batches

    // ---- general path only: fp32 inv-std per (bi,row) ----
    if (hc) {
        if (lane < 32) {
            const int bi = lane >> 4, s = lane & 15;
            const float* xr = xw + (bi * SS + s) * DI;
            float xv[DI]; float sum = 0.f;
            #pragma unroll
            for (int d = 0; d < DI; ++d) { xv[d] = xr[d]; sum += xv[d]; }
            const float mu = sum * (1.0f / (float)DI);
            float vs = 0.f;
            #pragma unroll
            for (int d = 0; d < DI; ++d) { const float t = xv[d] - mu; vs += t * t; }
            irsS[w][bi][s] = 1.0f / sqrtf(vs * (1.0f / (float)DI) + 1e-5f);
        }
        __builtin_amdgcn_wave_barrier();
    }

    // ---- A fragments for both batches (lanes 0..31; slabs 2,3 stay zero) ----
    s16x8 ah[2] = {{0,0,0,0,0,0,0,0}, {0,0,0,0,0,0,0,0}};
    s16x8 al[2] = {{0,0,0,0,0,0,0,0}, {0,0,0,0,0,0,0,0}};
    if (lane < 32) {
        #pragma unroll
        for (int bi = 0; bi < 2; ++bi) {
            const float* xr = xw + (bi * SS + l) * DI;
            float xv[8];
            if (g == 0) {
                #pragma unroll
                for (int i = 0; i < 4; ++i) {
                    const v2f p = *(const v2f*)(xr + 2 * i);
                    xv[2 * i] = p.x; xv[2 * i + 1] = p.y;
                }
            } else {
                #pragma unroll
                for (int i = 0; i < 3; ++i) {
                    const v2f p = *(const v2f*)(xr + 8 + 2 * i);
                    xv[2 * i] = p.x; xv[2 * i + 1] = p.y;
                }
                xv[6] = hc ? irsS[w][bi][l] : 0.f;   // dim14: irs (general path)
                xv[7] = 0.f;
            }
            #pragma unroll
            for (int i = 0; i < 8; ++i) {
                const unsigned short h = bf16_rne(xv[i]);
                const float r = xv[i] - bf16_to_f32(h);
                ah[bi][i] = (short)h;
                al[bi][i] = (short)bf16_rne(r);
            }
        }
    }

    // ---- scan: tiles outer, batches inner; parity trackers ----
    float t0v[2][4], t1v[2][4]; int t0j[2][4], t1j[2][4];
    #pragma unroll
    for (int bi = 0; bi < 2; ++bi)
        #pragma unroll
        for (int r = 0; r < 4; ++r) {
            t0v[bi][r] = -INFINITY; t1v[bi][r] = -INFINITY;
            t0j[bi][r] = 0;         t1j[bi][r] = 1;
        }
    const f32x4 z4 = {0.f, 0.f, 0.f, 0.f};

    #pragma unroll
    for (int t = 0; t < 16; ++t) {
        s16x8 bh = {0,0,0,0,0,0,0,0}, bl = {0,0,0,0,0,0,0,0};
        if (lane < 32) { bh = bhiS[t * 32 + lane]; bl = bloS[t * 32 + lane]; }
        #pragma unroll
        for (int bi = 0; bi < 2; ++bi) {
            f32x4 acc = __builtin_amdgcn_mfma_f32_16x16x32_bf16(al[bi], bh, z4, 0, 0, 0);
            acc = __builtin_amdgcn_mfma_f32_16x16x32_bf16(ah[bi], bl, acc, 0, 0, 0);
            acc = __builtin_amdgcn_mfma_f32_16x16x32_bf16(ah[bi], bh, acc, 0, 0, 0);
            #pragma unroll
            for (int r = 0; r < 4; ++r) {
                const float s = acc[r];
                if (t & 1) {
                    const bool c = s > t1v[bi][r];
                    t1v[bi][r] = c ? s : t1v[bi][r]; t1j[bi][r] = c ? t : t1j[bi][r];
                } else {
                    const bool c = s > t0v[bi][r];
                    t0v[bi][r] = c ? s : t0v[bi][r]; t0j[bi][r] = c ? t : t0j[bi][r];
                }
            }
        }
    }

    // ---- top-2 tournament per 16-lane group: u32 keys + ds_swizzle ----
    #pragma unroll
    for (int bi = 0; bi < 2; ++bi) {
        unsigned kh[4], kl[4];
        #pragma unroll
        for (int r = 0; r < 4; ++r) {
            const unsigned k0 = key32(t0v[bi][r], t0j[bi][r] * 16 + l);
            const unsigned k1 = key32(t1v[bi][r], t1j[bi][r] * 16 + l);
            kh[r] = k0 > k1 ? k0 : k1;
            kl[r] = k0 > k1 ? k1 : k0;
        }
        #pragma unroll
        for (int r = 0; r < 4; ++r) {
            {   // xor 8
                const unsigned oh = swz<0x201F>(kh[r]), ol = swz<0x201F>(kl[r]);
                const unsigned mn = kh[r] < oh ? kh[r] : oh;
                kh[r] = kh[r] > oh ? kh[r] : oh;
                const unsigned mx = kl[r] > ol ? kl[r] : ol;
                kl[r] = mn > mx ? mn : mx;
            }
            {   // xor 4
                const unsigned oh = swz<0x101F>(kh[r]), ol = swz<0x101F>(kl[r]);
                const unsigned mn = kh[r] < oh ? kh[r] : oh;
                kh[r] = kh[r] > oh ? kh[r] : oh;
                const unsigned mx = kl[r] > ol ? kl[r] : ol;
                kl[r] = mn > mx ? mn : mx;
            }
            {   // xor 2
                const unsigned oh = swz<0x081F>(kh[r]), ol = swz<0x081F>(kl[r]);
                const unsigned mn = kh[r] < oh ? kh[r] : oh;
                kh[r] = kh[r] > oh ? kh[r] : oh;
                const unsigned mx = kl[r] > ol ? kl[r] : ol;
                kl[r] = mn > mx ? mn : mx;
            }
            {   // xor 1
                const unsigned oh = swz<0x041F>(kh[r]), ol = swz<0x041F>(kl[r]);
                const unsigned mn = kh[r] < oh ? kh[r] : oh;
                kh[r] = kh[r] > oh ? kh[r] : oh;
                const unsigned mx = kl[r] > ol ? kl[r] : ol;
                kl[r] = mn > mx ? mn : mx;
            }
        }
        if (l == 0) {
            #pragma unroll
            for (int r = 0; r < 4; ++r) {
                jcandS[w][bi][g * 4 + r][0] = 255 - (int)(kh[r] & 0xFFu);
                jcandS[w][bi][g * 4 + r][1] = 255 - (int)(kl[r] & 0xFFu);
            }
        }
    }
    __builtin_amdgcn_wave_barrier();

    // ---- fp64 rescore: exactly 1 task per lane (2 bi x 16 rows x 2 cands) ----
    {
        const int bi = lane >> 5, row = (lane >> 1) & 15, ci = lane & 1;
        const int j = jcandS[w][bi][row][ci];
        const float* xr = xw + (bi * SS + row) * DI;
        double a = 0.0;
        #pragma unroll
        for (int d2 = 0; d2 < 7; ++d2) {
            const v2f xp = *(const v2f*)(xr + 2 * d2);
            const double2 mv = mpack[d2 * 256 + j];
            a += (double)xp.x * mv.x + (double)xp.y * mv.y;
        }
        if (hc) {   // general path: + irs64 * c_j
            double xv[DI]; double sum = 0.0;
            #pragma unroll
            for (int d = 0; d < DI; ++d) { xv[d] = (double)xr[d]; sum += xv[d]; }
            const double mu = sum * (1.0 / (double)DI);
            double vs = 0.0;
            #pragma unroll
            for (int d = 0; d < DI; ++d) { const double t = xv[d] - mu; vs += t * t; }
            const double irs64 = 1.0 / sqrt(vs * (1.0 / (double)DI) + 1e-5);
            a += irs64 * cvec[j];
        }
        const double oa = __shfl_xor(a, 1);
        const int    oj = __shfl_xor(j, 1);
        const int jwin = (a > oa || (a == oa && j < oj)) ? j : oj;
        if (ci == 0) jstarS[w][bi][row] = jwin;
    }
    __builtin_amdgcn_wave_barrier();

    // ---- head: z fp64 (14 lanes = 2 bi x 7 classes), softmax fp32 ----
    if (lane < 2 * NC) {
        const int bi = lane >= NC ? 1 : 0;
        const int c  = lane - bi * NC;
        double zv = zbs[c];
        #pragma unroll
        for (int s = 0; s < SS; ++s)
            zv += (double)wbs[s] * (double)Ts[jstarS[w][bi][s] * NC + c];
        zrowd[w][bi][c] = zv;
    }
    __builtin_amdgcn_wave_barrier();
    if (lane < 2 * NC) {
        const int bi = lane >= NC ? 1 : 0;
        const int c  = lane - bi * NC;
        double m = zrowd[w][bi][0];
        #pragma unroll
        for (int c2 = 1; c2 < NC; ++c2) m = fmax(m, zrowd[w][bi][c2]);
        float den = 0.f;
        #pragma unroll
        for (int c2 = 0; c2 < NC; ++c2) den += __expf((float)(zrowd[w][bi][c2] - m));
        const float num = __expf((float)(zrowd[w][bi][c] - m));
        out[(size_t)gw * 2 * NC + lane] = num / den;
    }
}

extern "C" void kernel_launch(void* const* d_in, const int* in_sizes, int n_in,
                              void* d_out, int out_size, void* d_ws, size_t ws_size,
                              hipStream_t stream) {
    const float* x      = (const float*)d_in[0];
    const float* lookup = (const float*)d_in[1];
    const float* g_st   = (const float*)d_in[2];
    const float* b_st   = (const float*)d_in[3];
    const float* g_sp   = (const float*)d_in[4];
    const float* b_sp   = (const float*)d_in[5];
    const float* g_pp   = (const float*)d_in[6];
    const float* b_pp   = (const float*)d_in[7];
    const float* Wv     = (const float*)d_in[8];
    const float* Wo     = (const float*)d_in[9];
    const float* Wm     = (const float*)d_in[10];
    const float* bm     = (const float*)d_in[11];
    const float* Wb     = (const float*)d_in[12];
    const float* bb     = (const float*)d_in[13];

    double2* mpack = (double2*)((char*)d_ws + WS_MPACK_OFF);
    float*   Tf    = (float*)((char*)d_ws + WS_TF_OFF);
    double*  zbp   = (double*)((char*)d_ws + WS_ZB_OFF);
    double*  cvec  = (double*)((char*)d_ws + WS_CV_OFF);
    int*     hc    = (int*)((char*)d_ws + WS_HC_OFF);

    precompute_kernel<<<1, 256, 0, stream>>>(lookup, g_st, b_st, g_pp, b_pp,
                                             g_sp, b_sp,
                                             Wv, Wo, Wm, bm, Wb, bb,
                                             mpack, Tf, zbp, cvec, hc);
    hopfield_kernel<<<NBLK, 256, 0, stream>>>(x, mpack, cvec, hc, Tf, zbp, Wb,
                                              (float*)d_out);
}

// Round 4
// 153.167 us; speedup vs baseline: 1.2105x; 1.2105x over previous
//
#include <hip/hip_runtime.h>
#include <math.h>

// Problem constants (fixed by setup_inputs)
#define BATCH 32768
#define SS 16          // bands / sequence
#define DI 14          // input dim
#define BQ 256         // stored patterns
#define NC 7           // classes
#define NBLK 2048      // 4 waves/block -> 8192 waves, 4 contiguous batches/wave

// ws layout:
//   mpack : double2[7][256]  (28672 B) m-tilde = g_sp*k - (S/14), packed dim-pairs x pattern
//   Tf    : float[256*7]     ( 7168 B) per-pattern class contribution table
//   zb    : double[7]        (   56 B) bm[c]*sum(Wb) + bb
//   cvec  : double[256]      ( 2048 B) c_j = b_sp . k_j   (all 0 for these inputs)
//   hc    : int              (    4 B) any(b_sp != 0)
#define WS_MPACK_OFF 0
#define WS_TF_OFF    28672
#define WS_ZB_OFF    35840
#define WS_CV_OFF    35896
#define WS_HC_OFF    37944

typedef float  f32x4 __attribute__((ext_vector_type(4)));
typedef short  s16x8 __attribute__((ext_vector_type(8)));
typedef float  v2f   __attribute__((ext_vector_type(2)));

__device__ __forceinline__ unsigned short bf16_rne(float f) {
    unsigned u = __float_as_uint(f);
    unsigned r = u + 0x7FFFu + ((u >> 16) & 1u);
    return (unsigned short)(r >> 16);
}
__device__ __forceinline__ float bf16_to_f32(unsigned short h) {
    return __uint_as_float(((unsigned)h) << 16);
}

// Monotone fp32->u32 order map, top 24 bits kept, low byte = (255-j).
// u32 compare == "score desc, then lowest j" at 2^-16 relative quantization —
// below the bf16-split scan error; fp64 rescore covers both error tiers.
__device__ __forceinline__ unsigned key32(float v, int j) {
    unsigned u = __float_as_uint(v);
    u ^= ((unsigned)((int)u >> 31)) | 0x80000000u;
    return (u & 0xFFFFFF00u) | (unsigned)(255 - j);
}

// xor-butterfly exchange via ds_swizzle (immediate pattern, no address VALU).
// BitMode offset = (xor<<10) | (or<<5) | and, and=0x1F, or=0.
template<int PAT>
__device__ __forceinline__ unsigned swz(unsigned v) {
    return (unsigned)__builtin_amdgcn_ds_swizzle((int)v, PAT);
}

__global__ __launch_bounds__(256) void precompute_kernel(
    const float* __restrict__ lookup,
    const float* __restrict__ g_st, const float* __restrict__ b_st,
    const float* __restrict__ g_pp, const float* __restrict__ b_pp,
    const float* __restrict__ g_sp, const float* __restrict__ b_sp,
    const float* __restrict__ Wv,  const float* __restrict__ Wo,
    const float* __restrict__ Wm,  const float* __restrict__ bm,
    const float* __restrict__ Wb,  const float* __restrict__ bb,
    double2* __restrict__ mpack, float* __restrict__ Tf, double* __restrict__ zb,
    double* __restrict__ cvec, int* __restrict__ hc)
{
    __shared__ double G1s[256][7];   // (Wo.T @ Wm.T)  : [p][c]
    __shared__ double Gs[14][7];     // Wv.T @ G1      : [d][c]
    const int tid = threadIdx.x;

    // G1[p][c] = sum_o Wo[o,p] * Wm[c,o]
    {
        const int p = tid;
        for (int c = 0; c < NC; ++c) {
            double acc = 0.0;
            for (int o = 0; o < 28; ++o)
                acc += (double)Wo[o * 256 + p] * (double)Wm[c * 28 + o];
            G1s[p][c] = acc;
        }
    }
    __syncthreads();
    // G[d][c] = sum_p Wv[p,d] * G1[p][c]
    if (tid < DI * NC) {
        const int d = tid / NC, c = tid % NC;
        double acc = 0.0;
        for (int p = 0; p < 256; ++p)
            acc += (double)Wv[p * DI + d] * G1s[p][c];
        Gs[d][c] = acc;
    }
    __syncthreads();

    // Per stored pattern j: LayerNorm once (fp64), emit m-tilde, c_j, T row.
    {
        const int j = tid;
        double xr[DI];
        double sum = 0.0;
        for (int d = 0; d < DI; ++d) { xr[d] = (double)lookup[j * DI + d]; sum += xr[d]; }
        const double mu = sum * (1.0 / (double)DI);
        double vs = 0.0;
        for (int d = 0; d < DI; ++d) { const double t = xr[d] - mu; vs += t * t; }
        const double rs = 1.0 / sqrt(vs * (1.0 / (double)DI) + 1e-5);

        double kj[DI], vl[DI];
        for (int d = 0; d < DI; ++d) {
            const double nrm = (xr[d] - mu) * rs;
            kj[d] = nrm * (double)g_st[d] + (double)b_st[d];
            vl[d] = nrm * (double)g_pp[d] + (double)b_pp[d];
        }
        // m_j = g_sp .* k_j ; m~_j = m_j - (sum m_j)/14 ; c_j = b_sp . k_j
        double mv[DI], S = 0.0, cj = 0.0;
        for (int d = 0; d < DI; ++d) {
            mv[d] = kj[d] * (double)g_sp[d];
            S += mv[d];
            cj += (double)b_sp[d] * kj[d];
        }
        const double Sm = S * (1.0 / (double)DI);
        for (int d2 = 0; d2 < DI / 2; ++d2) {
            double2 p; p.x = mv[2 * d2] - Sm; p.y = mv[2 * d2 + 1] - Sm;
            mpack[d2 * 256 + j] = p;
        }
        cvec[j] = cj;

        for (int c = 0; c < NC; ++c) {
            double acc = 0.0;
            for (int d = 0; d < DI; ++d) acc += vl[d] * Gs[d][c];
            Tf[j * NC + c] = (float)acc;
        }
    }
    if (tid < NC) {
        double wbsum = 0.0;
        for (int s = 0; s < SS; ++s) wbsum += (double)Wb[s];
        zb[tid] = (double)bm[tid] * wbsum + (double)bb[0];
    }
    if (tid == 0) {
        int f = 0;
        for (int d = 0; d < DI; ++d) f |= (b_sp[d] != 0.0f) ? 1 : 0;
        *hc = f;
    }
}

// One wave = 4 contiguous batches (single superstep, no grid loop).
// Batch loop OUTER, tile loop inner, trackers scoped per batch iteration —
// the low-register-pressure structure proven at 66 us (R2 / 60 VGPR, no spill).
// Single change vs that kernel: top-2 tournament uses u32 keys + ds_swizzle
// (immediate lane pattern, no address VALU, 1-cyc u32 max) instead of fp64
// denormal keys + fp64 shuffles. fp64 rescore still makes the final pick.
__global__ __launch_bounds__(256, 4) void hopfield_kernel(
    const float* __restrict__ x,
    const double2* __restrict__ mpack, const double* __restrict__ cvec,
    const int* __restrict__ hcp,
    const float* __restrict__ Tf, const double* __restrict__ zb,
    const float* __restrict__ Wb, float* __restrict__ out)
{
    __shared__ s16x8  bhiS[16 * 32];          // B hi frags  [tile][lane<32]  8 KiB
    __shared__ s16x8  bloS[16 * 32];          // B lo frags                   8 KiB
    __shared__ float  Ts[256 * NC];           //                              7 KiB
    __shared__ double zbs[NC];
    __shared__ float  wbs[SS];
    __shared__ int    jcandS[4][4][SS][2];    // [wave][bi][row][cand]
    __shared__ int    jstarS[4][4][SS];
    __shared__ double zrowd[4][4][NC];
    __shared__ float  irsS[4][4][SS];         // general path only (hc != 0)

    const int tid  = threadIdx.x;
    const int lane = tid & 63;
    const int w    = tid >> 6;
    const int g    = lane >> 4;   // A k-slab / C row-group
    const int l    = lane & 15;   // A row (band) / C col (pattern sub-idx)
    const int hc   = *hcp;

    // ---- stage B fragments (hi/lo bf16 splits of fp32(m~)), thread = pattern j ----
    {
        const int j = tid;
        float mf[16];
        #pragma unroll
        for (int d2 = 0; d2 < 7; ++d2) {
            const double2 mv = mpack[d2 * 256 + j];
            mf[2 * d2] = (float)mv.x; mf[2 * d2 + 1] = (float)mv.y;
        }
        mf[14] = (float)cvec[j];   // pairs with A dim14 = irs (general path; 0 here)
        mf[15] = 0.f;
        #pragma unroll
        for (int ks = 0; ks < 2; ++ks) {
            s16x8 h8, l8;
            #pragma unroll
            for (int i = 0; i < 8; ++i) {
                const float f = mf[8 * ks + i];
                const unsigned short h = bf16_rne(f);
                const float r = f - bf16_to_f32(h);     // exact (Sterbenz)
                h8[i] = (short)h;
                l8[i] = (short)bf16_rne(r);
            }
            bhiS[(j >> 4) * 32 + ks * 16 + (j & 15)] = h8;
            bloS[(j >> 4) * 32 + ks * 16 + (j & 15)] = l8;
        }
    }
    for (int i = tid; i < 256 * NC; i += 256) Ts[i] = Tf[i];
    if (tid < NC) zbs[tid] = zb[tid];
    if (tid < SS) wbs[tid] = Wb[tid];
    __syncthreads();

    const int gw = blockIdx.x * 4 + w;               // 0..8191
    const float* xw = x + (size_t)gw * 4 * SS * DI;  // this wave's 4 batches

    // ---- general path only: fp32 inv-std per (bi,row) ----
    if (hc) {
        const int bi = lane >> 4, s = lane & 15;
        const float* xr = xw + (bi * SS + s) * DI;
        float xv[DI]; float sum = 0.f;
        #pragma unroll
        for (int d = 0; d < DI; ++d) { xv[d] = xr[d]; sum += xv[d]; }
        const float mu = sum * (1.0f / (float)DI);
        float vs = 0.f;
        #pragma unroll
        for (int d = 0; d < DI; ++d) { const float t = xv[d] - mu; vs += t * t; }
        irsS[w][bi][s] = 1.0f / sqrtf(vs * (1.0f / (float)DI) + 1e-5f);
        __builtin_amdgcn_wave_barrier();
    }

    // ---- scan: 4 batches, 16 MFMA tiles each; trackers scoped per batch ----
    for (int bi = 0; bi < 4; ++bi) {
        s16x8 ah = {0,0,0,0,0,0,0,0}, al = {0,0,0,0,0,0,0,0};
        if (lane < 32) {   // k-slabs 0,1 hold real dims; slabs 2,3 stay zero
            const float* xr = xw + (bi * SS + l) * DI;
            float xv[8];
            if (g == 0) {
                #pragma unroll
                for (int i = 0; i < 4; ++i) {
                    const v2f p = *(const v2f*)(xr + 2 * i);
                    xv[2 * i] = p.x; xv[2 * i + 1] = p.y;
                }
            } else {
                #pragma unroll
                for (int i = 0; i < 3; ++i) {
                    const v2f p = *(const v2f*)(xr + 8 + 2 * i);
                    xv[2 * i] = p.x; xv[2 * i + 1] = p.y;
                }
                xv[6] = hc ? irsS[w][bi][l] : 0.f;   // dim14: irs (general path)
                xv[7] = 0.f;
            }
            #pragma unroll
            for (int i = 0; i < 8; ++i) {
                const unsigned short h = bf16_rne(xv[i]);
                const float r = xv[i] - bf16_to_f32(h);
                ah[i] = (short)h;
                al[i] = (short)bf16_rne(r);
            }
        }

        float t0v[4], t1v[4]; int t0j[4], t1j[4];
        #pragma unroll
        for (int r = 0; r < 4; ++r) {
            t0v[r] = -INFINITY; t1v[r] = -INFINITY; t0j[r] = 0; t1j[r] = 1;
        }
        const f32x4 z4 = {0.f, 0.f, 0.f, 0.f};

        #pragma unroll
        for (int t = 0; t < 16; ++t) {
            s16x8 bh = {0,0,0,0,0,0,0,0}, bl = {0,0,0,0,0,0,0,0};
            if (lane < 32) { bh = bhiS[t * 32 + lane]; bl = bloS[t * 32 + lane]; }
            f32x4 acc = __builtin_amdgcn_mfma_f32_16x16x32_bf16(al, bh, z4, 0, 0, 0);
            acc = __builtin_amdgcn_mfma_f32_16x16x32_bf16(ah, bl, acc, 0, 0, 0);
            acc = __builtin_amdgcn_mfma_f32_16x16x32_bf16(ah, bh, acc, 0, 0, 0);
            #pragma unroll
            for (int r = 0; r < 4; ++r) {
                const float s = acc[r];
                if (t & 1) {
                    const bool c = s > t1v[r];
                    t1v[r] = c ? s : t1v[r]; t1j[r] = c ? t : t1j[r];
                } else {
                    const bool c = s > t0v[r];
                    t0v[r] = c ? s : t0v[r]; t0j[r] = c ? t : t0j[r];
                }
            }
        }

        // ---- top-2 tournament per 16-lane group: u32 keys + ds_swizzle ----
        unsigned kh[4], kl[4];
        #pragma unroll
        for (int r = 0; r < 4; ++r) {
            const unsigned k0 = key32(t0v[r], t0j[r] * 16 + l);
            const unsigned k1 = key32(t1v[r], t1j[r] * 16 + l);
            kh[r] = k0 > k1 ? k0 : k1;
            kl[r] = k0 > k1 ? k1 : k0;
        }
        #pragma unroll
        for (int r = 0; r < 4; ++r) {
            {   // xor 8
                const unsigned oh = swz<0x201F>(kh[r]), ol = swz<0x201F>(kl[r]);
                const unsigned mn = kh[r] < oh ? kh[r] : oh;
                kh[r] = kh[r] > oh ? kh[r] : oh;
                const unsigned mx = kl[r] > ol ? kl[r] : ol;
                kl[r] = mn > mx ? mn : mx;
            }
            {   // xor 4
                const unsigned oh = swz<0x101F>(kh[r]), ol = swz<0x101F>(kl[r]);
                const unsigned mn = kh[r] < oh ? kh[r] : oh;
                kh[r] = kh[r] > oh ? kh[r] : oh;
                const unsigned mx = kl[r] > ol ? kl[r] : ol;
                kl[r] = mn > mx ? mn : mx;
            }
            {   // xor 2
                const unsigned oh = swz<0x081F>(kh[r]), ol = swz<0x081F>(kl[r]);
                const unsigned mn = kh[r] < oh ? kh[r] : oh;
                kh[r] = kh[r] > oh ? kh[r] : oh;
                const unsigned mx = kl[r] > ol ? kl[r] : ol;
                kl[r] = mn > mx ? mn : mx;
            }
            {   // xor 1
                const unsigned oh = swz<0x041F>(kh[r]), ol = swz<0x041F>(kl[r]);
                const unsigned mn = kh[r] < oh ? kh[r] : oh;
                kh[r] = kh[r] > oh ? kh[r] : oh;
                const unsigned mx = kl[r] > ol ? kl[r] : ol;
                kl[r] = mn > mx ? mn : mx;
            }
        }
        if (l == 0) {
            #pragma unroll
            for (int r = 0; r < 4; ++r) {
                jcandS[w][bi][g * 4 + r][0] = 255 - (int)(kh[r] & 0xFFu);
                jcandS[w][bi][g * 4 + r][1] = 255 - (int)(kl[r] & 0xFFu);
            }
        }
    }
    __builtin_amdgcn_wave_barrier();

    // ---- fp64 rescore: 128 tasks (4 bi x 16 rows x 2 cands) on 64 lanes x 2 ----
    #pragma unroll
    for (int u = 0; u < 2; ++u) {
        const int task = u * 64 + lane;
        const int bi = task >> 5, row = (task >> 1) & 15, ci = task & 1;
        const int j = jcandS[w][bi][row][ci];
        const float* xr = xw + (bi * SS + row) * DI;
        double a = 0.0;
        #pragma unroll
        for (int d2 = 0; d2 < 7; ++d2) {
            const v2f xp = *(const v2f*)(xr + 2 * d2);
            const double2 mv = mpack[d2 * 256 + j];
            a += (double)xp.x * mv.x + (double)xp.y * mv.y;
        }
        if (hc) {   // general path: + irs64 * c_j
            double xv[DI]; double sum = 0.0;
            #pragma unroll
            for (int d = 0; d < DI; ++d) { xv[d] = (double)xr[d]; sum += xv[d]; }
            const double mu = sum * (1.0 / (double)DI);
            double vs = 0.0;
            #pragma unroll
            for (int d = 0; d < DI; ++d) { const double t = xv[d] - mu; vs += t * t; }
            const double irs64 = 1.0 / sqrt(vs * (1.0 / (double)DI) + 1e-5);
            a += irs64 * cvec[j];
        }
        const double oa = __shfl_xor(a, 1);
        const int    oj = __shfl_xor(j, 1);
        const int jwin = (a > oa || (a == oa && j < oj)) ? j : oj;
        if ((lane & 1) == 0) jstarS[w][bi][row] = jwin;
    }
    __builtin_amdgcn_wave_barrier();

    // ---- head: z fp64 (28 lanes = 4 bi x 7 classes), softmax fp32 ----
    if (lane < 4 * NC) {
        const int bi = lane / NC, c = lane % NC;
        double zv = zbs[c];
        #pragma unroll
        for (int s = 0; s < SS; ++s)
            zv += (double)wbs[s] * (double)Ts[jstarS[w][bi][s] * NC + c];
        zrowd[w][bi][c] = zv;
    }
    __builtin_amdgcn_wave_barrier();
    if (lane < 4 * NC) {
        const int bi = lane / NC;
        double m = zrowd[w][bi][0];
        #pragma unroll
        for (int c2 = 1; c2 < NC; ++c2) m = fmax(m, zrowd[w][bi][c2]);
        float den = 0.f;
        #pragma unroll
        for (int c2 = 0; c2 < NC; ++c2) den += __expf((float)(zrowd[w][bi][c2] - m));
        const float num = __expf((float)(zrowd[w][bi][lane % NC] - m));
        out[(size_t)gw * 28 + lane] = num / den;
    }
}

extern "C" void kernel_launch(void* const* d_in, const int* in_sizes, int n_in,
                              void* d_out, int out_size, void* d_ws, size_t ws_size,
                              hipStream_t stream) {
    const float* x      = (const float*)d_in[0];
    const float* lookup = (const float*)d_in[1];
    const float* g_st   = (const float*)d_in[2];
    const float* b_st   = (const float*)d_in[3];
    const float* g_sp   = (const float*)d_in[4];
    const float* b_sp   = (const float*)d_in[5];
    const float* g_pp   = (const float*)d_in[6];
    const float* b_pp   = (const float*)d_in[7];
    const float* Wv     = (const float*)d_in[8];
    const float* Wo     = (const float*)d_in[9];
    const float* Wm     = (const float*)d_in[10];
    const float* bm     = (const float*)d_in[11];
    const float* Wb     = (const float*)d_in[12];
    const float* bb     = (const float*)d_in[13];

    double2* mpack = (double2*)((char*)d_ws + WS_MPACK_OFF);
    float*   Tf    = (float*)((char*)d_ws + WS_TF_OFF);
    double*  zbp   = (double*)((char*)d_ws + WS_ZB_OFF);
    double*  cvec  = (double*)((char*)d_ws + WS_CV_OFF);
    int*     hc    = (int*)((char*)d_ws + WS_HC_OFF);

    precompute_kernel<<<1, 256, 0, stream>>>(lookup, g_st, b_st, g_pp, b_pp,
                                             g_sp, b_sp,
                                             Wv, Wo, Wm, bm, Wb, bb,
                                             mpack, Tf, zbp, cvec, hc);
    hopfield_kernel<<<NBLK, 256, 0, stream>>>(x, mpack, cvec, hc, Tf, zbp, Wb,
                                              (float*)d_out);
}

// Round 6
// 150.417 us; speedup vs baseline: 1.2326x; 1.0183x over previous
//
#include <hip/hip_runtime.h>
#include <math.h>

// Problem constants (fixed by setup_inputs)
#define BATCH 32768
#define SS 16          // bands / sequence
#define DI 14          // input dim
#define BQ 256         // stored patterns
#define NC 7           // classes
#define NBLK 2048      // 4 waves/block -> 8192 waves, 4 contiguous batches/wave

// ws layout:
//   mpack : double2[7][256]  (28672 B) m-tilde = g_sp*k - (S/14), packed dim-pairs x pattern
//   Tf    : float[256*7]     ( 7168 B) per-pattern class contribution table
//   zb    : double[7]        (   56 B) bm[c]*sum(Wb) + bb
//   cvec  : double[256]      ( 2048 B) c_j = b_sp . k_j   (all 0 for these inputs)
//   hc    : int              (    4 B) any(b_sp != 0)
#define WS_MPACK_OFF 0
#define WS_TF_OFF    28672
#define WS_ZB_OFF    35840
#define WS_CV_OFF    35896
#define WS_HC_OFF    37944

typedef float  f32x4 __attribute__((ext_vector_type(4)));
typedef short  s16x8 __attribute__((ext_vector_type(8)));
typedef float  v2f   __attribute__((ext_vector_type(2)));

__device__ __forceinline__ unsigned short bf16_rne(float f) {
    unsigned u = __float_as_uint(f);
    unsigned r = u + 0x7FFFu + ((u >> 16) & 1u);
    return (unsigned short)(r >> 16);
}
__device__ __forceinline__ float bf16_to_f32(unsigned short h) {
    return __uint_as_float(((unsigned)h) << 16);
}

// Monotone fp32->u32 order map, top 24 bits kept, low byte = (255-j).
// u32 compare == "score desc, then lowest j" at 2^-16 relative quantization —
// below the bf16-split scan error; fp64 rescore covers both error tiers.
__device__ __forceinline__ unsigned key32(float v, int j) {
    unsigned u = __float_as_uint(v);
    u ^= ((unsigned)((int)u >> 31)) | 0x80000000u;
    return (u & 0xFFFFFF00u) | (unsigned)(255 - j);
}

// xor-butterfly exchange via ds_swizzle (immediate pattern, no address VALU).
// BitMode offset = (xor<<10) | (or<<5) | and, and=0x1F, or=0.
template<int PAT>
__device__ __forceinline__ unsigned swz(unsigned v) {
    return (unsigned)__builtin_amdgcn_ds_swizzle((int)v, PAT);
}

__global__ __launch_bounds__(256) void precompute_kernel(
    const float* __restrict__ lookup,
    const float* __restrict__ g_st, const float* __restrict__ b_st,
    const float* __restrict__ g_pp, const float* __restrict__ b_pp,
    const float* __restrict__ g_sp, const float* __restrict__ b_sp,
    const float* __restrict__ Wv,  const float* __restrict__ Wo,
    const float* __restrict__ Wm,  const float* __restrict__ bm,
    const float* __restrict__ Wb,  const float* __restrict__ bb,
    double2* __restrict__ mpack, float* __restrict__ Tf, double* __restrict__ zb,
    double* __restrict__ cvec, int* __restrict__ hc)
{
    __shared__ double G1s[256][7];   // (Wo.T @ Wm.T)  : [p][c]
    __shared__ double Gs[14][7];     // Wv.T @ G1      : [d][c]
    const int tid = threadIdx.x;

    // G1[p][c] = sum_o Wo[o,p] * Wm[c,o]
    {
        const int p = tid;
        for (int c = 0; c < NC; ++c) {
            double acc = 0.0;
            for (int o = 0; o < 28; ++o)
                acc += (double)Wo[o * 256 + p] * (double)Wm[c * 28 + o];
            G1s[p][c] = acc;
        }
    }
    __syncthreads();
    // G[d][c] = sum_p Wv[p,d] * G1[p][c]
    if (tid < DI * NC) {
        const int d = tid / NC, c = tid % NC;
        double acc = 0.0;
        for (int p = 0; p < 256; ++p)
            acc += (double)Wv[p * DI + d] * G1s[p][c];
        Gs[d][c] = acc;
    }
    __syncthreads();

    // Per stored pattern j: LayerNorm once (fp64), emit m-tilde, c_j, T row.
    {
        const int j = tid;
        double xr[DI];
        double sum = 0.0;
        for (int d = 0; d < DI; ++d) { xr[d] = (double)lookup[j * DI + d]; sum += xr[d]; }
        const double mu = sum * (1.0 / (double)DI);
        double vs = 0.0;
        for (int d = 0; d < DI; ++d) { const double t = xr[d] - mu; vs += t * t; }
        const double rs = 1.0 / sqrt(vs * (1.0 / (double)DI) + 1e-5);

        double kj[DI], vl[DI];
        for (int d = 0; d < DI; ++d) {
            const double nrm = (xr[d] - mu) * rs;
            kj[d] = nrm * (double)g_st[d] + (double)b_st[d];
            vl[d] = nrm * (double)g_pp[d] + (double)b_pp[d];
        }
        // m_j = g_sp .* k_j ; m~_j = m_j - (sum m_j)/14 ; c_j = b_sp . k_j
        double mv[DI], S = 0.0, cj = 0.0;
        for (int d = 0; d < DI; ++d) {
            mv[d] = kj[d] * (double)g_sp[d];
            S += mv[d];
            cj += (double)b_sp[d] * kj[d];
        }
        const double Sm = S * (1.0 / (double)DI);
        for (int d2 = 0; d2 < DI / 2; ++d2) {
            double2 p; p.x = mv[2 * d2] - Sm; p.y = mv[2 * d2 + 1] - Sm;
            mpack[d2 * 256 + j] = p;
        }
        cvec[j] = cj;

        for (int c = 0; c < NC; ++c) {
            double acc = 0.0;
            for (int d = 0; d < DI; ++d) acc += vl[d] * Gs[d][c];
            Tf[j * NC + c] = (float)acc;
        }
    }
    if (tid < NC) {
        double wbsum = 0.0;
        for (int s = 0; s < SS; ++s) wbsum += (double)Wb[s];
        zb[tid] = (double)bm[tid] * wbsum + (double)bb[0];
    }
    if (tid == 0) {
        int f = 0;
        for (int d = 0; d < DI; ++d) f |= (b_sp[d] != 0.0f) ? 1 : 0;
        *hc = f;
    }
}

// One wave = 4 contiguous batches. MFMA operands swapped vs R4:
// acc = mfma(pattern_frag, x_frag, .) -> C[p_sub][band]: col=lane&15=band,
// row=(lane>>4)*4+reg=pattern-sub. Each lane scores 64 patterns IN-LANE for
// one band (j = t*16 + (lane>>4)*4 + r).
// Coverage fix vs failed R5: 8 trackers per lane indexed by (r, t&1) — the
// compile-time tracker choice keeps the 3-op update, and the induced cells
// {j = m mod 16, t parity} of size 8 are IDENTICAL to R4's proven partition.
// Tournament: in-lane top-2 tree over 8 class champions, then xor16
// (ds_swizzle) + xor32 (shfl) merges. fp64 rescore of top-2 unchanged.
// Ts dropped from LDS (head reads Tf from L2) -> ~21.5 KB -> 7 blocks/CU.
__global__ __launch_bounds__(256, 4) void hopfield_kernel(
    const float* __restrict__ x,
    const double2* __restrict__ mpack, const double* __restrict__ cvec,
    const int* __restrict__ hcp,
    const float* __restrict__ Tf, const double* __restrict__ zb,
    const float* __restrict__ Wb, float* __restrict__ out)
{
    __shared__ s16x8  bhiS[16 * 32];          // pattern hi frags [tile][lane<32]  8 KiB
    __shared__ s16x8  bloS[16 * 32];          // pattern lo frags                  8 KiB
    __shared__ double zbs[NC];
    __shared__ float  wbs[SS];
    __shared__ int    jcandS[4][4][SS][2];    // [wave][bi][band][cand]
    __shared__ int    jstarS[4][4][SS];
    __shared__ double zrowd[4][4][NC];
    __shared__ float  irsS[4][4][SS];         // general path only (hc != 0)

    const int tid  = threadIdx.x;
    const int lane = tid & 63;
    const int w    = tid >> 6;
    const int g    = lane >> 4;   // k-slab (frags) / pattern-sub group (C rows)
    const int l    = lane & 15;   // band (x-frag row and C col)
    const int hc   = *hcp;

    // ---- stage pattern fragments (hi/lo bf16 splits of fp32(m~)), thread = pattern j ----
    {
        const int j = tid;
        float mf[16];
        #pragma unroll
        for (int d2 = 0; d2 < 7; ++d2) {
            const double2 mv = mpack[d2 * 256 + j];
            mf[2 * d2] = (float)mv.x; mf[2 * d2 + 1] = (float)mv.y;
        }
        mf[14] = (float)cvec[j];   // pairs with x dim14 = irs (general path; 0 here)
        mf[15] = 0.f;
        #pragma unroll
        for (int ks = 0; ks < 2; ++ks) {
            s16x8 h8, l8;
            #pragma unroll
            for (int i = 0; i < 8; ++i) {
                const float f = mf[8 * ks + i];
                const unsigned short h = bf16_rne(f);
                const float r = f - bf16_to_f32(h);     // exact (Sterbenz)
                h8[i] = (short)h;
                l8[i] = (short)bf16_rne(r);
            }
            bhiS[(j >> 4) * 32 + ks * 16 + (j & 15)] = h8;
            bloS[(j >> 4) * 32 + ks * 16 + (j & 15)] = l8;
        }
    }
    if (tid < NC) zbs[tid] = zb[tid];
    if (tid < SS) wbs[tid] = Wb[tid];
    __syncthreads();

    const int gw = blockIdx.x * 4 + w;               // 0..8191
    const float* xw = x + (size_t)gw * 4 * SS * DI;  // this wave's 4 batches

    // ---- general path only: fp32 inv-std per (bi,row) ----
    if (hc) {
        const int bi = lane >> 4, s = lane & 15;
        const float* xr = xw + (bi * SS + s) * DI;
        float xv[DI]; float sum = 0.f;
        #pragma unroll
        for (int d = 0; d < DI; ++d) { xv[d] = xr[d]; sum += xv[d]; }
        const float mu = sum * (1.0f / (float)DI);
        float vs = 0.f;
        #pragma unroll
        for (int d = 0; d < DI; ++d) { const float t = xv[d] - mu; vs += t * t; }
        irsS[w][bi][s] = 1.0f / sqrtf(vs * (1.0f / (float)DI) + 1e-5f);
        __builtin_amdgcn_wave_barrier();
    }

    // ---- scan: 4 batches, 16 MFMA tiles each; 8 in-lane trackers per band ----
    for (int bi = 0; bi < 4; ++bi) {
        s16x8 xh = {0,0,0,0,0,0,0,0}, xl = {0,0,0,0,0,0,0,0};
        if (lane < 32) {   // k-slabs 0,1 hold real dims; slabs 2,3 stay zero
            const float* xr = xw + (bi * SS + l) * DI;
            float xv[8];
            if (g == 0) {
                #pragma unroll
                for (int i = 0; i < 4; ++i) {
                    const v2f p = *(const v2f*)(xr + 2 * i);
                    xv[2 * i] = p.x; xv[2 * i + 1] = p.y;
                }
            } else {
                #pragma unroll
                for (int i = 0; i < 3; ++i) {
                    const v2f p = *(const v2f*)(xr + 8 + 2 * i);
                    xv[2 * i] = p.x; xv[2 * i + 1] = p.y;
                }
                xv[6] = hc ? irsS[w][bi][l] : 0.f;   // dim14: irs (general path)
                xv[7] = 0.f;
            }
            #pragma unroll
            for (int i = 0; i < 8; ++i) {
                const unsigned short h = bf16_rne(xv[i]);
                const float r = xv[i] - bf16_to_f32(h);
                xh[i] = (short)h;
                xl[i] = (short)bf16_rne(r);
            }
        }

        // 8 trackers: (r, t&1). Compile-time indices in the unrolled loops ->
        // update stays cmp+2*cndmask per score. Cells of 8 patterns, identical
        // j-partition to the proven R4 scheme.
        float tv[4][2]; int ti[4][2];
        #pragma unroll
        for (int r = 0; r < 4; ++r) {
            tv[r][0] = -INFINITY; tv[r][1] = -INFINITY;
            ti[r][0] = 0;         ti[r][1] = 1;
        }
        const f32x4 z4 = {0.f, 0.f, 0.f, 0.f};

        #pragma unroll
        for (int t = 0; t < 16; ++t) {
            s16x8 ph = {0,0,0,0,0,0,0,0}, pl = {0,0,0,0,0,0,0,0};
            if (lane < 32) { ph = bhiS[t * 32 + lane]; pl = bloS[t * 32 + lane]; }
            // A = pattern (M=pattern-sub), B = x (N=band)
            f32x4 acc = __builtin_amdgcn_mfma_f32_16x16x32_bf16(pl, xh, z4, 0, 0, 0);
            acc = __builtin_amdgcn_mfma_f32_16x16x32_bf16(ph, xl, acc, 0, 0, 0);
            acc = __builtin_amdgcn_mfma_f32_16x16x32_bf16(ph, xh, acc, 0, 0, 0);
            #pragma unroll
            for (int r = 0; r < 4; ++r) {
                const float s = acc[r];
                if (t & 1) {
                    const bool c = s > tv[r][1];
                    tv[r][1] = c ? s : tv[r][1]; ti[r][1] = c ? t : ti[r][1];
                } else {
                    const bool c = s > tv[r][0];
                    tv[r][0] = c ? s : tv[r][0]; ti[r][0] = c ? t : ti[r][0];
                }
            }
        }

        // ---- in-lane top-2 tree over the 8 class champions ----
        const int jbase = (lane & 0x30) >> 2;   // (lane>>4)*4
        unsigned h4[4], l4[4];
        #pragma unroll
        for (int r = 0; r < 4; ++r) {
            const unsigned k0 = key32(tv[r][0], ti[r][0] * 16 + jbase + r);
            const unsigned k1 = key32(tv[r][1], ti[r][1] * 16 + jbase + r);
            h4[r] = k0 > k1 ? k0 : k1;
            l4[r] = k0 > k1 ? k1 : k0;
        }
        unsigned H0, L0, H1, L1, kh, kl;
        {   const unsigned mn = h4[0] < h4[1] ? h4[0] : h4[1];
            H0 = h4[0] > h4[1] ? h4[0] : h4[1];
            const unsigned mx = l4[0] > l4[1] ? l4[0] : l4[1];
            L0 = mn > mx ? mn : mx; }
        {   const unsigned mn = h4[2] < h4[3] ? h4[2] : h4[3];
            H1 = h4[2] > h4[3] ? h4[2] : h4[3];
            const unsigned mx = l4[2] > l4[3] ? l4[2] : l4[3];
            L1 = mn > mx ? mn : mx; }
        {   const unsigned mn = H0 < H1 ? H0 : H1;
            kh = H0 > H1 ? H0 : H1;
            const unsigned mx = L0 > L1 ? L0 : L1;
            kl = mn > mx ? mn : mx; }

        {   // merge across lane^16 (ds_swizzle, within 32-lane group)
            const unsigned oh = swz<0x401F>(kh), ol = swz<0x401F>(kl);
            const unsigned mn = kh < oh ? kh : oh;
            kh = kh > oh ? kh : oh;
            const unsigned mx = kl > ol ? kl : ol;
            kl = mn > mx ? mn : mx;
        }
        {   // merge across lane^32 (shfl)
            const unsigned oh = (unsigned)__shfl_xor((int)kh, 32);
            const unsigned ol = (unsigned)__shfl_xor((int)kl, 32);
            const unsigned mn = kh < oh ? kh : oh;
            kh = kh > oh ? kh : oh;
            const unsigned mx = kl > ol ? kl : ol;
            kl = mn > mx ? mn : mx;
        }
        if (lane < 16) {
            jcandS[w][bi][lane][0] = 255 - (int)(kh & 0xFFu);
            jcandS[w][bi][lane][1] = 255 - (int)(kl & 0xFFu);
        }
    }
    __builtin_amdgcn_wave_barrier();

    // ---- fp64 rescore: 128 tasks (4 bi x 16 bands x 2 cands) on 64 lanes x 2 ----
    #pragma unroll
    for (int u = 0; u < 2; ++u) {
        const int task = u * 64 + lane;
        const int bi = task >> 5, row = (task >> 1) & 15, ci = task & 1;
        const int j = jcandS[w][bi][row][ci];
        const float* xr = xw + (bi * SS + row) * DI;
        double a = 0.0;
        #pragma unroll
        for (int d2 = 0; d2 < 7; ++d2) {
            const v2f xp = *(const v2f*)(xr + 2 * d2);
            const double2 mv = mpack[d2 * 256 + j];
            a += (double)xp.x * mv.x + (double)xp.y * mv.y;
        }
        if (hc) {   // general path: + irs64 * c_j
            double xv[DI]; double sum = 0.0;
            #pragma unroll
            for (int d = 0; d < DI; ++d) { xv[d] = (double)xr[d]; sum += xv[d]; }
            const double mu = sum * (1.0 / (double)DI);
            double vs = 0.0;
            #pragma unroll
            for (int d = 0; d < DI; ++d) { const double t = xv[d] - mu; vs += t * t; }
            const double irs64 = 1.0 / sqrt(vs * (1.0 / (double)DI) + 1e-5);
            a += irs64 * cvec[j];
        }
        const double oa = __shfl_xor(a, 1);
        const int    oj = __shfl_xor(j, 1);
        const int jwin = (a > oa || (a == oa && j < oj)) ? j : oj;
        if ((lane & 1) == 0) jstarS[w][bi][row] = jwin;
    }
    __builtin_amdgcn_wave_barrier();

    // ---- head: z fp64 (28 lanes = 4 bi x 7 classes), Tf from global (L2) ----
    if (lane < 4 * NC) {
        const int bi = lane / NC, c = lane % NC;
        double zv = zbs[c];
        #pragma unroll
        for (int s = 0; s < SS; ++s)
            zv += (double)wbs[s] * (double)Tf[jstarS[w][bi][s] * NC + c];
        zrowd[w][bi][c] = zv;
    }
    __builtin_amdgcn_wave_barrier();
    if (lane < 4 * NC) {
        const int bi = lane / NC;
        double m = zrowd[w][bi][0];
        #pragma unroll
        for (int c2 = 1; c2 < NC; ++c2) m = fmax(m, zrowd[w][bi][c2]);
        float den = 0.f;
        #pragma unroll
        for (int c2 = 0; c2 < NC; ++c2) den += __expf((float)(zrowd[w][bi][c2] - m));
        const float num = __expf((float)(zrowd[w][bi][lane % NC] - m));
        out[(size_t)gw * 28 + lane] = num / den;
    }
}

extern "C" void kernel_launch(void* const* d_in, const int* in_sizes, int n_in,
                              void* d_out, int out_size, void* d_ws, size_t ws_size,
                              hipStream_t stream) {
    const float* x      = (const float*)d_in[0];
    const float* lookup = (const float*)d_in[1];
    const float* g_st   = (const float*)d_in[2];
    const float* b_st   = (const float*)d_in[3];
    const float* g_sp   = (const float*)d_in[4];
    const float* b_sp   = (const float*)d_in[5];
    const float* g_pp   = (const float*)d_in[6];
    const float* b_pp   = (const float*)d_in[7];
    const float* Wv     = (const float*)d_in[8];
    const float* Wo     = (const float*)d_in[9];
    const float* Wm     = (const float*)d_in[10];
    const float* bm     = (const float*)d_in[11];
    const float* Wb     = (const float*)d_in[12];
    const float* bb     = (const float*)d_in[13];

    double2* mpack = (double2*)((char*)d_ws + WS_MPACK_OFF);
    float*   Tf    = (float*)((char*)d_ws + WS_TF_OFF);
    double*  zbp   = (double*)((char*)d_ws + WS_ZB_OFF);
    double*  cvec  = (double*)((char*)d_ws + WS_CV_OFF);
    int*     hc    = (int*)((char*)d_ws + WS_HC_OFF);

    precompute_kernel<<<1, 256, 0, stream>>>(lookup, g_st, b_st, g_pp, b_pp,
                                             g_sp, b_sp,
                                             Wv, Wo, Wm, bm, Wb, bb,
                                             mpack, Tf, zbp, cvec, hc);
    hopfield_kernel<<<NBLK, 256, 0, stream>>>(x, mpack, cvec, hc, Tf, zbp, Wb,
                                              (float*)d_out);
}